// Round 1
// baseline (616.502 us; speedup 1.0000x reference)
//
#include <hip/hip_runtime.h>
#include <hip/hip_bf16.h>

#define BB 2048
#define NN 128
#define DD 256
#define HH 8
#define TT 64

typedef __bf16 bf16x8 __attribute__((ext_vector_type(8)));
typedef float f32x4 __attribute__((ext_vector_type(4)));

static __device__ __forceinline__ f32x4 mfma16(bf16x8 a, bf16x8 b, f32x4 c) {
  return __builtin_amdgcn_mfma_f32_16x16x32_bf16(a, b, c, 0, 0, 0);
}

static __device__ __forceinline__ f32x4 zero4() {
  f32x4 z = {0.f, 0.f, 0.f, 0.f};
  return z;
}

static __device__ __forceinline__ bf16x8 cvt8(const float* p) {
  const float4 x0 = *(const float4*)p;
  const float4 x1 = *(const float4*)(p + 4);
  bf16x8 r;
  r[0] = (__bf16)x0.x; r[1] = (__bf16)x0.y; r[2] = (__bf16)x0.z; r[3] = (__bf16)x0.w;
  r[4] = (__bf16)x1.x; r[5] = (__bf16)x1.y; r[6] = (__bf16)x1.z; r[7] = (__bf16)x1.w;
  return r;
}

// -------- fold1: 5 D x D products, one block per output row --------
// p0: W_TQ  = Wq_m @ W_target   -> bf16 [i][j]
// p1: W_GQT = (Wq_m @ W_global) stored transposed -> f32 [j][i]
// p2: W_KH  = Wk_m @ W_K1       -> bf16 [i][j]
// p3: W_VH  = Wv_m @ W_V        -> bf16 [i][j]
// p4: W_QO  = W_Q  @ Wo_m       -> f32  [i][j]
__global__ void fold1(const float* __restrict__ Wq_m, const float* __restrict__ W_target,
                      const float* __restrict__ W_global, const float* __restrict__ Wk_m,
                      const float* __restrict__ W_K1, const float* __restrict__ Wv_m,
                      const float* __restrict__ W_V, const float* __restrict__ W_Q,
                      const float* __restrict__ Wo_m,
                      __bf16* __restrict__ WTQ, float* __restrict__ WGQT,
                      __bf16* __restrict__ WKH, __bf16* __restrict__ WVH,
                      float* __restrict__ WQO) {
  const int p = blockIdx.x >> 8;
  const int i = blockIdx.x & 255;
  const int t = threadIdx.x;
  __shared__ float arow[256];
  const float* A;
  const float* Bm;
  if (p == 0)      { A = Wq_m; Bm = W_target; }
  else if (p == 1) { A = Wq_m; Bm = W_global; }
  else if (p == 2) { A = Wk_m; Bm = W_K1; }
  else if (p == 3) { A = Wv_m; Bm = W_V; }
  else             { A = W_Q;  Bm = Wo_m; }
  arow[t] = A[i * 256 + t];
  __syncthreads();
  float acc = 0.f;
  for (int k = 0; k < 256; ++k) acc = fmaf(arow[k], Bm[k * 256 + t], acc);
  if (p == 0)      WTQ[i * 256 + t] = (__bf16)acc;
  else if (p == 1) WGQT[t * 256 + i] = acc;
  else if (p == 2) WKH[i * 256 + t] = (__bf16)acc;
  else if (p == 3) WVH[i * 256 + t] = (__bf16)acc;
  else             WQO[i * 256 + t] = acc;
}

// -------- fold2: WZL[j][i] = sum_d WQO[d][i] * W_K2[d][j]  (bf16) --------
__global__ void fold2(const float* __restrict__ WQO, const float* __restrict__ W_K2,
                      __bf16* __restrict__ WZL) {
  const int j = blockIdx.x;
  const int t = threadIdx.x;
  __shared__ float col[256];
  col[t] = W_K2[t * 256 + j];
  __syncthreads();
  float acc = 0.f;
  for (int d = 0; d < 256; ++d) acc = fmaf(WQO[d * 256 + t], col[d], acc);
  WZL[j * 256 + t] = (__bf16)acc;
}

// -------- gq: GQ[b][i] = sum_j WGQT[j][i] * graph_emb[b][j]  (f32) --------
__global__ void gq_kernel(const float* __restrict__ ge, const float* __restrict__ WGQT,
                          float* __restrict__ GQ) {
  const int b = blockIdx.x;
  const int t = threadIdx.x;
  __shared__ float g[256];
  g[t] = ge[b * 256 + t];
  __syncthreads();
  float acc = 0.f;
  for (int j = 0; j < 256; ++j) acc = fmaf(WGQT[j * 256 + t], g[j], acc);
  GQ[b * 256 + t] = acc;
}

// -------- glimpse: per-b block; Q GEMM + per-head KH/VH proj + attention --------
__global__ __launch_bounds__(256, 2)
void glimpse_kernel(const float* __restrict__ E, const int* __restrict__ tg,
                    const __bf16* __restrict__ WTQ, const __bf16* __restrict__ WKH,
                    const __bf16* __restrict__ WVH, const float* __restrict__ GQ,
                    __bf16* __restrict__ HO) {
  const int b = blockIdx.x;
  const int tid = threadIdx.x;
  const int w = tid >> 6;
  const int l = tid & 63;
  const int lr = l & 15;
  const int lg = l >> 4;

  __shared__ __bf16 Qs[64 * 264];   // Q rows [64][256], stride 264 (2-way max conflicts)
  __shared__ __bf16 KHs[128 * 40];  // KH_h [128 nodes][32 d], stride 40
  __shared__ __bf16 VTs[32 * 136];  // VH_h transposed [32 d][128 nodes], stride 136
  __shared__ __bf16 Ps[64 * 136];   // P-hat [64 t][128 n], stride 136
  __shared__ int tgs[64];

  if (tid < 64) tgs[tid] = tg[tid * BB + b];
  __syncthreads();

  const float* Eb = E + (size_t)b * NN * DD;

  // ---- Phase 1: Q[t][:] = E[b][tgt[t]] @ WTQ^T + GQ[b]  -> Qs (bf16)
  {
    f32x4 acc[4][4];
#pragma unroll
    for (int mf = 0; mf < 4; ++mf)
#pragma unroll
      for (int nf = 0; nf < 4; ++nf) acc[mf][nf] = zero4();
    const int n0 = w * 64;
    for (int kk = 0; kk < 8; ++kk) {
      bf16x8 aF[4], bF[4];
#pragma unroll
      for (int mf = 0; mf < 4; ++mf) {
        const int node = tgs[mf * 16 + lr];
        aF[mf] = cvt8(Eb + node * DD + kk * 32 + lg * 8);
      }
#pragma unroll
      for (int nf = 0; nf < 4; ++nf)
        bF[nf] = *(const bf16x8*)(WTQ + (size_t)(n0 + nf * 16 + lr) * DD + kk * 32 + lg * 8);
#pragma unroll
      for (int mf = 0; mf < 4; ++mf)
#pragma unroll
        for (int nf = 0; nf < 4; ++nf) acc[mf][nf] = mfma16(aF[mf], bF[nf], acc[mf][nf]);
    }
#pragma unroll
    for (int nf = 0; nf < 4; ++nf) {
      const int col = n0 + nf * 16 + lr;
      const float g = GQ[b * DD + col];
#pragma unroll
      for (int mf = 0; mf < 4; ++mf)
#pragma unroll
        for (int r = 0; r < 4; ++r)
          Qs[(mf * 16 + lg * 4 + r) * 264 + col] = (__bf16)(acc[mf][nf][r] + g);
    }
  }

  // ---- Per-head loop
  for (int h = 0; h < HH; ++h) {
    __syncthreads();  // protect KHs/VTs reuse (and Qs visibility at h=0)
    // KH_h = E[b] @ WKH[h]^T ; VH_h = E[b] @ WVH[h]^T (shared A frags)
    {
      f32x4 ak[2][2], av[2][2];
#pragma unroll
      for (int mf = 0; mf < 2; ++mf)
#pragma unroll
        for (int nf = 0; nf < 2; ++nf) { ak[mf][nf] = zero4(); av[mf][nf] = zero4(); }
      for (int kk = 0; kk < 8; ++kk) {
        bf16x8 aF[2], bK[2], bV[2];
#pragma unroll
        for (int mf = 0; mf < 2; ++mf)
          aF[mf] = cvt8(Eb + (w * 32 + mf * 16 + lr) * DD + kk * 32 + lg * 8);
#pragma unroll
        for (int nf = 0; nf < 2; ++nf) {
          const size_t wo = (size_t)(h * 32 + nf * 16 + lr) * DD + kk * 32 + lg * 8;
          bK[nf] = *(const bf16x8*)(WKH + wo);
          bV[nf] = *(const bf16x8*)(WVH + wo);
        }
#pragma unroll
        for (int mf = 0; mf < 2; ++mf)
#pragma unroll
          for (int nf = 0; nf < 2; ++nf) {
            ak[mf][nf] = mfma16(aF[mf], bK[nf], ak[mf][nf]);
            av[mf][nf] = mfma16(aF[mf], bV[nf], av[mf][nf]);
          }
      }
#pragma unroll
      for (int mf = 0; mf < 2; ++mf)
#pragma unroll
        for (int nf = 0; nf < 2; ++nf)
#pragma unroll
          for (int r = 0; r < 4; ++r) {
            const int node = w * 32 + mf * 16 + lg * 4 + r;
            const int d = nf * 16 + lr;
            KHs[node * 40 + d] = (__bf16)ak[mf][nf][r];
            VTs[d * 136 + node] = (__bf16)av[mf][nf][r];
          }
    }
    __syncthreads();
    // S = Q_h @ KH_h^T (wave w owns t rows [16w,16w+16)), softmax, PV
    {
      const bf16x8 aq = *(const bf16x8*)&Qs[(w * 16 + lr) * 264 + h * 32 + lg * 8];
      f32x4 s[8];
#pragma unroll
      for (int nf = 0; nf < 8; ++nf)
        s[nf] = mfma16(aq, *(const bf16x8*)&KHs[(nf * 16 + lr) * 40 + lg * 8], zero4());

      float mx[4] = {-1e30f, -1e30f, -1e30f, -1e30f};
#pragma unroll
      for (int nf = 0; nf < 8; ++nf)
#pragma unroll
        for (int r = 0; r < 4; ++r) mx[r] = fmaxf(mx[r], s[nf][r]);
#pragma unroll
      for (int mk = 1; mk <= 8; mk <<= 1)
#pragma unroll
        for (int r = 0; r < 4; ++r) mx[r] = fmaxf(mx[r], __shfl_xor(mx[r], mk));

      float ev[8][4];
      float sm[4] = {0.f, 0.f, 0.f, 0.f};
#pragma unroll
      for (int nf = 0; nf < 8; ++nf)
#pragma unroll
        for (int r = 0; r < 4; ++r) {
          ev[nf][r] = __expf((s[nf][r] - mx[r]) * 0.17677669529663687f);
          sm[r] += ev[nf][r];
        }
#pragma unroll
      for (int mk = 1; mk <= 8; mk <<= 1)
#pragma unroll
        for (int r = 0; r < 4; ++r) sm[r] += __shfl_xor(sm[r], mk);

#pragma unroll
      for (int nf = 0; nf < 8; ++nf)
#pragma unroll
        for (int r = 0; r < 4; ++r)
          Ps[(w * 16 + lg * 4 + r) * 136 + nf * 16 + lr] = (__bf16)ev[nf][r];

      // PV: same-wave LDS write->read (in-order DS pipe, may-alias keeps compiler honest)
      f32x4 o[2] = {zero4(), zero4()};
#pragma unroll
      for (int kk = 0; kk < 4; ++kk) {
        const bf16x8 ap = *(const bf16x8*)&Ps[(w * 16 + lr) * 136 + kk * 32 + lg * 8];
#pragma unroll
        for (int nf2 = 0; nf2 < 2; ++nf2)
          o[nf2] = mfma16(ap, *(const bf16x8*)&VTs[(nf2 * 16 + lr) * 136 + kk * 32 + lg * 8],
                          o[nf2]);
      }
      float inv[4];
#pragma unroll
      for (int r = 0; r < 4; ++r) inv[r] = 1.f / sm[r];
#pragma unroll
      for (int nf2 = 0; nf2 < 2; ++nf2)
#pragma unroll
        for (int r = 0; r < 4; ++r) {
          const int t = w * 16 + lg * 4 + r;
          HO[((size_t)t * BB + b) * DD + h * 32 + nf2 * 16 + lr] =
              (__bf16)(o[nf2][r] * inv[r]);
        }
    }
  }
}

// -------- logits: per-b block; Z = HO @ WZL^T ; logits = Z @ E[b]^T ; LSE --------
__global__ __launch_bounds__(256, 2)
void logits_kernel(const float* __restrict__ E, const __bf16* __restrict__ HO,
                   const __bf16* __restrict__ WZL, const int* __restrict__ MK,
                   float* __restrict__ out) {
  const int b = blockIdx.x;
  const int tid = threadIdx.x;
  const int w = tid >> 6;
  const int l = tid & 63;
  const int lr = l & 15;
  const int lg = l >> 4;

  __shared__ __bf16 HOs[64 * 264];
  __shared__ __bf16 Zs[64 * 264];
  __shared__ float red[4];

#pragma unroll
  for (int it = 0; it < 8; ++it) {
    const int lin = it * 256 + tid;
    const int tr = lin >> 5;
    const int c8 = lin & 31;
    *(bf16x8*)&HOs[tr * 264 + c8 * 8] =
        *(const bf16x8*)(HO + ((size_t)tr * BB + b) * DD + c8 * 8);
  }
  __syncthreads();

  // Z: wave w computes cols [64w, 64w+64) for all 64 rows
  {
    f32x4 acc[4][4];
#pragma unroll
    for (int mf = 0; mf < 4; ++mf)
#pragma unroll
      for (int nf = 0; nf < 4; ++nf) acc[mf][nf] = zero4();
    for (int kk = 0; kk < 8; ++kk) {
      bf16x8 aF[4], bF[4];
#pragma unroll
      for (int mf = 0; mf < 4; ++mf)
        aF[mf] = *(const bf16x8*)&HOs[(mf * 16 + lr) * 264 + kk * 32 + lg * 8];
#pragma unroll
      for (int nf = 0; nf < 4; ++nf)
        bF[nf] = *(const bf16x8*)(WZL + (size_t)(w * 64 + nf * 16 + lr) * DD + kk * 32 + lg * 8);
#pragma unroll
      for (int mf = 0; mf < 4; ++mf)
#pragma unroll
        for (int nf = 0; nf < 4; ++nf) acc[mf][nf] = mfma16(aF[mf], bF[nf], acc[mf][nf]);
    }
#pragma unroll
    for (int mf = 0; mf < 4; ++mf)
#pragma unroll
      for (int nf = 0; nf < 4; ++nf)
#pragma unroll
        for (int r = 0; r < 4; ++r)
          Zs[(mf * 16 + lg * 4 + r) * 264 + w * 64 + nf * 16 + lr] = (__bf16)acc[mf][nf][r];
  }
  __syncthreads();

  // logits rows t0 = 16w over all 128 nodes; B-operand = raw E[b] (f32 -> bf16)
  {
    const float* Eb = E + (size_t)b * NN * DD;
    f32x4 sa[8];
#pragma unroll
    for (int nf = 0; nf < 8; ++nf) sa[nf] = zero4();
    for (int kk = 0; kk < 8; ++kk) {
      const bf16x8 az = *(const bf16x8*)&Zs[(w * 16 + lr) * 264 + kk * 32 + lg * 8];
#pragma unroll
      for (int nf = 0; nf < 8; ++nf) {
        const bf16x8 be = cvt8(Eb + (nf * 16 + lr) * DD + kk * 32 + lg * 8);
        sa[nf] = mfma16(az, be, sa[nf]);
      }
    }
    float xv[8][4];
    float mx[4] = {-3e38f, -3e38f, -3e38f, -3e38f};
    float sm[4] = {0.f, 0.f, 0.f, 0.f};
#pragma unroll
    for (int nf = 0; nf < 8; ++nf)
#pragma unroll
      for (int r = 0; r < 4; ++r) {
        const int t = w * 16 + lg * 4 + r;
        const int n = nf * 16 + lr;
        const int m = MK[((size_t)t * BB + b) * NN + n];
        const float x = 10.f * tanhf(sa[nf][r] * 0.0625f) - (float)m * 1e9f;
        xv[nf][r] = x;
        mx[r] = fmaxf(mx[r], x);
      }
#pragma unroll
    for (int mk = 1; mk <= 8; mk <<= 1)
#pragma unroll
      for (int r = 0; r < 4; ++r) mx[r] = fmaxf(mx[r], __shfl_xor(mx[r], mk));
#pragma unroll
    for (int nf = 0; nf < 8; ++nf)
#pragma unroll
      for (int r = 0; r < 4; ++r) sm[r] += __expf(xv[nf][r] - mx[r]);
#pragma unroll
    for (int mk = 1; mk <= 8; mk <<= 1)
#pragma unroll
      for (int r = 0; r < 4; ++r) sm[r] += __shfl_xor(sm[r], mk);

    float part = logf(sm[0]) + logf(sm[1]) + logf(sm[2]) + logf(sm[3]);
    part += __shfl_xor(part, 16);
    part += __shfl_xor(part, 32);
    if (l == 0) red[w] = part;
  }
  __syncthreads();
  if (tid == 0) out[b] = -(red[0] + red[1] + red[2] + red[3]);
}

extern "C" void kernel_launch(void* const* d_in, const int* in_sizes, int n_in,
                              void* d_out, int out_size, void* d_ws, size_t ws_size,
                              hipStream_t stream) {
  (void)in_sizes; (void)n_in; (void)out_size; (void)ws_size;
  const float* node_emb  = (const float*)d_in[0];
  const float* graph_emb = (const float*)d_in[1];
  const float* W_target  = (const float*)d_in[2];
  const float* W_global  = (const float*)d_in[3];
  const float* W_K1      = (const float*)d_in[4];
  const float* W_K2      = (const float*)d_in[5];
  const float* W_Q       = (const float*)d_in[6];
  const float* W_V       = (const float*)d_in[7];
  const float* Wq_m      = (const float*)d_in[8];
  const float* Wk_m      = (const float*)d_in[9];
  const float* Wv_m      = (const float*)d_in[10];
  const float* Wo_m      = (const float*)d_in[11];
  const int* targets     = (const int*)d_in[12];
  const int* masks       = (const int*)d_in[13];

  char* p = (char*)d_ws;
  __bf16* HO  = (__bf16*)p; p += (size_t)TT * BB * DD * 2;
  __bf16* WTQ = (__bf16*)p; p += 256 * 256 * 2;
  __bf16* WKH = (__bf16*)p; p += 256 * 256 * 2;
  __bf16* WVH = (__bf16*)p; p += 256 * 256 * 2;
  __bf16* WZL = (__bf16*)p; p += 256 * 256 * 2;
  float* WGQT = (float*)p;  p += 256 * 256 * 4;
  float* WQO  = (float*)p;  p += 256 * 256 * 4;
  float* GQ   = (float*)p;  p += (size_t)BB * DD * 4;

  fold1<<<1280, 256, 0, stream>>>(Wq_m, W_target, W_global, Wk_m, W_K1, Wv_m, W_V, W_Q, Wo_m,
                                  WTQ, WGQT, WKH, WVH, WQO);
  fold2<<<256, 256, 0, stream>>>(WQO, W_K2, WZL);
  gq_kernel<<<BB, 256, 0, stream>>>(graph_emb, WGQT, GQ);
  glimpse_kernel<<<BB, 256, 0, stream>>>(node_emb, targets, WTQ, WKH, WVH, GQ, HO);
  logits_kernel<<<BB, 256, 0, stream>>>(node_emb, HO, WZL, masks, (float*)d_out);
}